// Round 10
// baseline (95.464 us; speedup 1.0000x reference)
//
#include <hip/hip_runtime.h>
#include <hip/hip_bf16.h>

typedef __bf16 bf16x8 __attribute__((ext_vector_type(8)));
typedef float  f32x4  __attribute__((ext_vector_type(4)));

static constexpr int D     = 128;
static constexpr int BATCH = 4096;
static constexpr int N     = 8192;
static constexpr int BT    = 128;               // tile
static constexpr int NT    = N / BT;            // 64
static constexpr int TRI   = NT * (NT + 1) / 2; // 2080

// ---------------- prep: build fragment-packed Fpack + norms + exact fp32 ab-diag ----------------
// Fpack byte(row, c=16B-chunk, off): tile=row>>7, slice=(row>>5)&3, half=(row>>4)&1, lr=row&15,
//   ks=c>>2, hk=c&3  ->  tile*32768 + slice*8192 + ks*2048 + half*1024 + hk*256 + lr*16 + off.
// Any MFMA fragment (16 rows x 16B chunk) is then a contiguous 1KB wave-read:
//   A side (wave wv, frag fi, phase ks): base + ti*32768 + wv*8192 + ks*2048 + fi*1024 + (hk*256+lr*16)
//   B side (frag fj, phase ks):          base + tj*32768 + (fj>>1)*8192 + ks*2048 + (fj&1)*1024 + (...)
__global__ __launch_bounds__(256) void prep_kernel(const float* __restrict__ f,
                                                   unsigned short* __restrict__ Fpack,
                                                   float* __restrict__ norms,
                                                   float* __restrict__ diag,
                                                   float* __restrict__ out) {
    if (blockIdx.x == 0 && threadIdx.x == 0) out[0] = 0.f;
    const int w = threadIdx.x >> 6, lane = threadIdx.x & 63;
    const int i = blockIdx.x * 4 + w;                 // 0..4095
    const float2 va = *(const float2*)(f + (size_t)i * D + lane * 2);
    const float2 vb = *(const float2*)(f + (size_t)(i + BATCH) * D + lane * 2);
    union { __bf16 h[2]; unsigned int u; } pa, pb;
    pa.h[0] = (__bf16)va.x; pa.h[1] = (__bf16)va.y;
    pb.h[0] = (__bf16)vb.x; pb.h[1] = (__bf16)vb.y;

    const int c   = lane >> 2;            // 16B chunk within row (0..15)
    const int off = (lane & 3) * 4;       // byte within chunk
    auto storeF = [&](int row, unsigned int bits) {
        char* p = (char*)Fpack + (size_t)(row >> 7) * 32768 + ((row >> 5) & 3) * 8192
                + (c >> 2) * 2048 + ((row >> 4) & 1) * 1024 + (c & 3) * 256 + (row & 15) * 16 + off;
        *(unsigned int*)p = bits;
    };
    storeF(i, pa.u);
    storeF(i + BATCH, pb.u);

    float na = va.x * va.x + va.y * va.y;
    float nb = vb.x * vb.x + vb.y * vb.y;
    const float dx = va.x - vb.x, dy = va.y - vb.y;
    float dd = dx * dx + dy * dy;
    #pragma unroll
    for (int m = 1; m <= 32; m <<= 1) {
        na += __shfl_xor(na, m); nb += __shfl_xor(nb, m); dd += __shfl_xor(dd, m);
    }
    if (lane == 0) {
        norms[i] = na; norms[i + BATCH] = nb;
        diag[i] = 1.f / (dd + 1.f);                   // exact fp32 cauchy diag of sim_ab
    }
}

// ---------------- 128x128 tile: zero-LDS, zero mid-kernel barriers, pure dataflow ----------------
// P[t][k][0..127]: k<=t row-partials of tile(t,k); k>t col-partials of tile(k,t). Exact-once writes.
__global__ __launch_bounds__(256, 4) void tile_kernel(const unsigned short* __restrict__ Fpack,
                                                      const float* __restrict__ norms,
                                                      float* __restrict__ P) {
    // XCD-chunked bijective swizzle (2080 % 8 == 0)
    const int bid = blockIdx.x;
    const int id = (bid & 7) * (TRI / 8) + (bid >> 3);
    int ti = (int)((sqrtf(8.f * (float)id + 1.f) - 1.f) * 0.5f);
    while ((ti + 1) * (ti + 2) / 2 <= id) ++ti;
    while (ti * (ti + 1) / 2 > id) --ti;
    const int tj = id - ti * (ti + 1) / 2;
    const bool diagblk = (ti == tj);

    __shared__ float colbuf[BT];

    const int tid = threadIdx.x, wv = tid >> 6, lane = tid & 63;
    const int lr = lane & 15, hk = lane >> 4;
    if (tid < BT) colbuf[tid] = 0.f;
    __syncthreads();                                   // colbuf init visible (start, no convoy)

    const char* Ab = (const char*)Fpack + (size_t)ti * 32768 + wv * 8192;
    const char* Bb = (const char*)Fpack + (size_t)tj * 32768;
    const int lo = hk * 256 + lr * 16;

    f32x4 acc[2][8];
    #pragma unroll
    for (int i = 0; i < 2; ++i)
        #pragma unroll
        for (int j = 0; j < 8; ++j)
            acc[i][j] = (f32x4){0.f, 0.f, 0.f, 0.f};

    #pragma unroll
    for (int ks = 0; ks < 4; ++ks) {
        bf16x8 av[2], bv[8];
        av[0] = *(const bf16x8*)(Ab + ks * 2048 + lo);
        av[1] = *(const bf16x8*)(Ab + ks * 2048 + 1024 + lo);
        #pragma unroll
        for (int fj = 0; fj < 8; ++fj)
            bv[fj] = *(const bf16x8*)(Bb + (fj >> 1) * 8192 + ks * 2048 + (fj & 1) * 1024 + lo);
        #pragma unroll
        for (int fj = 0; fj < 8; ++fj) {
            acc[0][fj] = __builtin_amdgcn_mfma_f32_16x16x32_bf16(av[0], bv[fj], acc[0][fj], 0, 0, 0);
            acc[1][fj] = __builtin_amdgcn_mfma_f32_16x16x32_bf16(av[1], bv[fj], acc[1][fj], 0, 0, 0);
        }
    }

    // ---- epilogue: sim transform + in-wave row sums + LDS-combined col partials ----
    float colN[8];
    #pragma unroll
    for (int fj = 0; fj < 8; ++fj)
        colN[fj] = norms[tj * BT + fj * 16 + lr];

    float* PR = P + ((size_t)ti * NT + tj) * BT;
    #pragma unroll
    for (int fi = 0; fi < 2; ++fi) {
        const int lrow = wv * 32 + fi * 16 + hk * 4;          // + r
        const f32x4 rN = *(const f32x4*)(norms + ti * BT + lrow);
        f32x4 rs = (f32x4){0.f, 0.f, 0.f, 0.f};
        #pragma unroll
        for (int fj = 0; fj < 8; ++fj) {
            const int lcol = fj * 16 + lr;
            #pragma unroll
            for (int r = 0; r < 4; ++r) {
                float sq = rN[r] + colN[fj] - 2.f * acc[fi][fj][r];
                sq = fmaxf(sq, 0.f);
                float sim = __builtin_amdgcn_rcpf(sq + 1.f);
                if (diagblk && (lrow + r == lcol)) sim = 0.f;  // self-mask
                rs[r] += sim;
                acc[fi][fj][r] = sim;
            }
        }
        #pragma unroll
        for (int r = 0; r < 4; ++r) {
            rs[r] += __shfl_xor(rs[r], 1);
            rs[r] += __shfl_xor(rs[r], 2);
            rs[r] += __shfl_xor(rs[r], 4);
            rs[r] += __shfl_xor(rs[r], 8);
        }
        if (lr == 0)
            *(f32x4*)(PR + lrow) = rs;                         // exact-once row writes
    }

    if (!diagblk) {
        #pragma unroll
        for (int fj = 0; fj < 8; ++fj) {
            float cs = 0.f;
            #pragma unroll
            for (int fi = 0; fi < 2; ++fi)
                #pragma unroll
                for (int r = 0; r < 4; ++r)
                    cs += acc[fi][fj][r];
            cs += __shfl_xor(cs, 16);
            cs += __shfl_xor(cs, 32);
            if (hk == 0)
                atomicAdd(&colbuf[fj * 16 + lr], cs);
        }
        __syncthreads();
        if (tid < BT)
            P[((size_t)tj * NT + ti) * BT + tid] = colbuf[tid]; // exact-once col writes
    }
}

// ---------------- finalize: uniform 64-slot sum per row, logs, scalar ----------------
__global__ __launch_bounds__(128) void finalize_kernel(const float* __restrict__ P,
                                                       const float* __restrict__ diag,
                                                       float* __restrict__ out) {
    const int t = blockIdx.x;            // 64 row-panels
    const int r = threadIdx.x;           // 128 rows per panel
    const float* base = P + (size_t)t * NT * BT + r;
    float s = 0.f;
    #pragma unroll 8
    for (int k = 0; k < NT; ++k) s += base[k * BT];
    const int i = t * BT + r;
    float term = 0.5f * __logf(s);
    if (i >= BATCH) term -= __logf(diag[i - BATCH]);
    #pragma unroll
    for (int m = 1; m <= 32; m <<= 1) term += __shfl_xor(term, m);
    if ((threadIdx.x & 63) == 0)
        atomicAdd(out, term / (float)BATCH);
}

extern "C" void kernel_launch(void* const* d_in, const int* in_sizes, int n_in,
                              void* d_out, int out_size, void* d_ws, size_t ws_size,
                              hipStream_t stream) {
    const float* feat = (const float*)d_in[0];
    char* ws = (char*)d_ws;
    // ws layout: Fpack 2MB @0 | norms 32KB @2MB | diag 16KB | P 2MB
    unsigned short* Fpack = (unsigned short*)ws;
    float* norms = (float*)(ws + (2u << 20));
    float* diag  = (float*)(ws + (2u << 20) + 32768);
    float* P     = (float*)(ws + (2u << 20) + 49152);
    float* out   = (float*)d_out;

    prep_kernel<<<BATCH / 4, 256, 0, stream>>>(feat, Fpack, norms, diag, out);
    tile_kernel<<<TRI, 256, 0, stream>>>(Fpack, norms, P);
    finalize_kernel<<<NT, 128, 0, stream>>>(P, diag, out);
}

// Round 13
// 78.717 us; speedup vs baseline: 1.2128x; 1.2128x over previous
//
#include <hip/hip_runtime.h>
#include <hip/hip_bf16.h>
#include <hip/hip_fp8.h>

typedef float f32x4 __attribute__((ext_vector_type(4)));
typedef int   i32x4 __attribute__((ext_vector_type(4)));
typedef int   i32x8 __attribute__((ext_vector_type(8)));

static constexpr int D     = 128;
static constexpr int BATCH = 4096;
static constexpr int N     = 8192;
static constexpr int BT    = 128;               // tile
static constexpr int NT    = N / BT;            // 64
static constexpr int TRI   = NT * (NT + 1) / 2; // 2080
static constexpr int SCALE1 = 0x7F7F7F7F;      // e8m0 scale bytes = 1.0

__device__ __forceinline__ void load_lds16(const void* g, void* l) {
    __builtin_amdgcn_global_load_lds(
        (const __attribute__((address_space(1))) unsigned int*)g,
        (__attribute__((address_space(3))) unsigned int*)l, 16, 0, 0);
}

// ---------------- prep: fp8 LDS-image pack + fp32 norms + exact fp32 ab-diag ----------------
// Image byte(row r, col k): (r>>7)*16384 + (r&127)*128 + (((k>>4) ^ (r&7))<<4) + (k&15)
// (16B-chunk XOR swizzle by row&7 -> conflict-free quarter-wave ds_read_b128, proven R5/R7)
__global__ __launch_bounds__(256) void prep_kernel(const float* __restrict__ f,
                                                   unsigned char* __restrict__ Fp8,
                                                   float* __restrict__ norms,
                                                   float* __restrict__ diag,
                                                   float* __restrict__ out) {
    if (blockIdx.x == 0 && threadIdx.x == 0) out[0] = 0.f;
    const int w = threadIdx.x >> 6, lane = threadIdx.x & 63;
    const int i = blockIdx.x * 4 + w;                 // 0..4095
    const float2 va = *(const float2*)(f + (size_t)i * D + lane * 2);
    const float2 vb = *(const float2*)(f + (size_t)(i + BATCH) * D + lane * 2);

    // pack 2 cols to e4m3 and store 2B into the pre-swizzled image
    auto storeF = [&](int row, float x, float y) {
        union { unsigned char b[2]; unsigned short u; } pk;
        pk.b[0] = __hip_fp8_e4m3(x).__x;
        pk.b[1] = __hip_fp8_e4m3(y).__x;
        const size_t dst = (size_t)(row >> 7) * 16384 + (row & 127) * 128
                         + (((lane >> 3) ^ (row & 7)) << 4) + (lane & 7) * 2;
        *(unsigned short*)(Fp8 + dst) = pk.u;
    };
    storeF(i, va.x, va.y);
    storeF(i + BATCH, vb.x, vb.y);

    float na = va.x * va.x + va.y * va.y;
    float nb = vb.x * vb.x + vb.y * vb.y;
    const float dx = va.x - vb.x, dy = va.y - vb.y;
    float dd = dx * dx + dy * dy;
    #pragma unroll
    for (int m = 1; m <= 32; m <<= 1) {
        na += __shfl_xor(na, m); nb += __shfl_xor(nb, m); dd += __shfl_xor(dd, m);
    }
    if (lane == 0) {
        norms[i] = na; norms[i + BATCH] = nb;
        diag[i] = 1.f / (dd + 1.f);                   // exact fp32 cauchy diag of sim_ab
    }
}

// ---------------- 128x128 tile: fp8 MX K=128 MFMA, single-phase 32KB stage, 4 blocks/CU ----------------
// P[t][k][0..127]: k<=t row-partials of tile(t,k); k>t col-partials of tile(k,t). Exact-once writes.
__global__ __launch_bounds__(256, 4) void tile_kernel(const unsigned char* __restrict__ Fp8,
                                                      const float* __restrict__ norms,
                                                      float* __restrict__ P) {
    // XCD-chunked bijective swizzle (2080 % 8 == 0)
    const int bid = blockIdx.x;
    const int id = (bid & 7) * (TRI / 8) + (bid >> 3);
    int ti = (int)((sqrtf(8.f * (float)id + 1.f) - 1.f) * 0.5f);
    while ((ti + 1) * (ti + 2) / 2 <= id) ++ti;
    while (ti * (ti + 1) / 2 > id) --ti;
    const int tj = id - ti * (ti + 1) / 2;
    const bool diagblk = (ti == tj);

    __shared__ __align__(16) unsigned char As[16384];  // fp8 A panel image (swizzled)
    __shared__ __align__(16) unsigned char Bs[16384];  // fp8 B panel image
    __shared__ float colbuf[BT];

    const int tid = threadIdx.x, wv = tid >> 6, lane = tid & 63;
    const int lr = lane & 15, hk = lane >> 4;
    if (tid < BT) colbuf[tid] = 0.f;

    // stage both 16KB images (identity copy; image is already the swizzled LDS layout)
    const unsigned char* Aimg = Fp8 + (size_t)ti * 16384;
    const unsigned char* Bimg = Fp8 + (size_t)tj * 16384;
    #pragma unroll
    for (int it = 0; it < 4; ++it)
        load_lds16(Aimg + (it * 256 + tid) * 16, As + it * 4096 + wv * 1024);
    #pragma unroll
    for (int it = 0; it < 4; ++it)
        load_lds16(Bimg + (it * 256 + tid) * 16, Bs + it * 4096 + wv * 1024);
    __syncthreads();

    // fragment read: row-group base + lane row lr, k-chunks (hk*2, hk*2+1) ^ (lr&7)
    auto frag = [&](const unsigned char* S, int rowbase) -> i32x8 {
        const int row = rowbase + lr;
        const i32x4 q0 = *(const i32x4*)(S + row * 128 + (((hk * 2 + 0) ^ (lr & 7)) << 4));
        const i32x4 q1 = *(const i32x4*)(S + row * 128 + (((hk * 2 + 1) ^ (lr & 7)) << 4));
        return __builtin_shufflevector(q0, q1, 0, 1, 2, 3, 4, 5, 6, 7);
    };

    f32x4 acc[2][8];
    #pragma unroll
    for (int i = 0; i < 2; ++i)
        #pragma unroll
        for (int j = 0; j < 8; ++j)
            acc[i][j] = (f32x4){0.f, 0.f, 0.f, 0.f};

    const i32x8 av0 = frag(As, wv * 32);
    const i32x8 av1 = frag(As, wv * 32 + 16);
    #pragma unroll
    for (int fj = 0; fj < 8; ++fj) {
        const i32x8 bv = frag(Bs, fj * 16);
        acc[0][fj] = __builtin_amdgcn_mfma_scale_f32_16x16x128_f8f6f4(
            av0, bv, acc[0][fj], 0, 0, 0, SCALE1, 0, SCALE1);
        acc[1][fj] = __builtin_amdgcn_mfma_scale_f32_16x16x128_f8f6f4(
            av1, bv, acc[1][fj], 0, 0, 0, SCALE1, 0, SCALE1);
    }

    // ---- epilogue: sim transform + in-wave row sums + LDS-combined col partials ----
    float colN[8];
    #pragma unroll
    for (int fj = 0; fj < 8; ++fj)
        colN[fj] = norms[tj * BT + fj * 16 + lr];

    float* PR = P + ((size_t)ti * NT + tj) * BT;
    #pragma unroll
    for (int fi = 0; fi < 2; ++fi) {
        const int lrow = wv * 32 + fi * 16 + hk * 4;          // + r
        const f32x4 rN = *(const f32x4*)(norms + ti * BT + lrow);
        f32x4 rs = (f32x4){0.f, 0.f, 0.f, 0.f};
        #pragma unroll
        for (int fj = 0; fj < 8; ++fj) {
            const int lcol = fj * 16 + lr;
            #pragma unroll
            for (int r = 0; r < 4; ++r) {
                float sq = rN[r] + colN[fj] - 2.f * acc[fi][fj][r];
                sq = fmaxf(sq, 0.f);
                float sim = __builtin_amdgcn_rcpf(sq + 1.f);
                if (diagblk && (lrow + r == lcol)) sim = 0.f;  // self-mask
                rs[r] += sim;
                acc[fi][fj][r] = sim;
            }
        }
        #pragma unroll
        for (int r = 0; r < 4; ++r) {
            rs[r] += __shfl_xor(rs[r], 1);
            rs[r] += __shfl_xor(rs[r], 2);
            rs[r] += __shfl_xor(rs[r], 4);
            rs[r] += __shfl_xor(rs[r], 8);
        }
        if (lr == 0)
            *(f32x4*)(PR + lrow) = rs;                         // exact-once row writes
    }

    if (!diagblk) {
        #pragma unroll
        for (int fj = 0; fj < 8; ++fj) {
            float cs = 0.f;
            #pragma unroll
            for (int fi = 0; fi < 2; ++fi)
                #pragma unroll
                for (int r = 0; r < 4; ++r)
                    cs += acc[fi][fj][r];
            cs += __shfl_xor(cs, 16);
            cs += __shfl_xor(cs, 32);
            if (hk == 0)
                atomicAdd(&colbuf[fj * 16 + lr], cs);
        }
        __syncthreads();
        if (tid < BT)
            P[((size_t)tj * NT + ti) * BT + tid] = colbuf[tid]; // exact-once col writes
    }
}

// ---------------- finalize: uniform 64-slot sum per row, logs, scalar ----------------
__global__ __launch_bounds__(128) void finalize_kernel(const float* __restrict__ P,
                                                       const float* __restrict__ diag,
                                                       float* __restrict__ out) {
    const int t = blockIdx.x;            // 64 row-panels
    const int r = threadIdx.x;           // 128 rows per panel
    const float* base = P + (size_t)t * NT * BT + r;
    float s = 0.f;
    #pragma unroll 8
    for (int k = 0; k < NT; ++k) s += base[k * BT];
    const int i = t * BT + r;
    float term = 0.5f * __logf(s);
    if (i >= BATCH) term -= __logf(diag[i - BATCH]);
    #pragma unroll
    for (int m = 1; m <= 32; m <<= 1) term += __shfl_xor(term, m);
    if ((threadIdx.x & 63) == 0)
        atomicAdd(out, term / (float)BATCH);
}

extern "C" void kernel_launch(void* const* d_in, const int* in_sizes, int n_in,
                              void* d_out, int out_size, void* d_ws, size_t ws_size,
                              hipStream_t stream) {
    const float* feat = (const float*)d_in[0];
    char* ws = (char*)d_ws;
    // ws layout: Fp8 image 1MB @0 | norms 32KB @1MB | diag 16KB | P 2MB
    unsigned char* Fp8 = (unsigned char*)ws;
    float* norms = (float*)(ws + (1u << 20));
    float* diag  = (float*)(ws + (1u << 20) + 32768);
    float* P     = (float*)(ws + (1u << 20) + 49152);
    float* out   = (float*)d_out;

    prep_kernel<<<BATCH / 4, 256, 0, stream>>>(feat, Fp8, norms, diag, out);
    tile_kernel<<<TRI, 256, 0, stream>>>(Fp8, norms, P);
    finalize_kernel<<<NT, 128, 0, stream>>>(P, diag, out);
}